// Round 10
// baseline (161.337 us; speedup 1.0000x reference)
//
#include <hip/hip_runtime.h>

#define S_TOTAL 17064
#define NB 16
#define NC 80
#define QPB 4266              // location-quads per batch image (sum hw/4)
#define NXQ 17                // quad-chunks of 256 for kernel B

// ---- kernel A chunk geometry (float4 units per (level,b) span = 20*hw) ----
// l0: 256000 f4 -> 96 chunks of 2667   l1: 64000 -> 24 x 2667
// l2: 16000 -> 6 x 2667                l3: 4160 -> 2 x 2080   l4: 1120 -> 1 x 1120
#define NA_BLOCKS 2064        // 16*(96+24+6+2+1)
#define SLOTS_PER_B 129       // cls partial slots per batch image
// ws layout: [0, 2064) A cls partials (b*129+slot); then 4 planes of 272 for B
#define WSB 2064
#define NBXQ (NB * NXQ)       // 272

typedef float vfloat4 __attribute__((ext_vector_type(4)));

struct Ptrs {
    const float* cls[5];
    const float* cnt[5];
    const float* reg[5];
    const float* cnt_t;   // [B,S,1]
    const float* reg_t;   // [B,S,4]
    const int*   cls_t;   // [B,S,1] int32 on device
    float*       ws;
    float*       out;
};

__device__ __forceinline__ float focal_term(float x, bool o) {
    const float xs = o ? x : -x;            // p_t = sigmoid(xs)
    const float af = o ? 0.25f : 0.75f;
    const float em = __expf(-xs);
    const float pt = 1.0f / (1.0f + em);
    const float q  = em * pt;               // 1 - p_t
    return af * q * q * __logf(1.0f + em);  // -af*(1-pt)^2*log(pt)
}

__device__ __forceinline__ float giou_term(float pl, float pt_, float pr, float pb,
                                           float tl, float tt, float tr, float tb) {
    const float overlap = fmaxf(fminf(pr, tr) + fminf(pl, tl), 0.0f) *
                          fmaxf(fminf(pb, tb) + fminf(pt_, tt), 0.0f);
    const float area1 = (pr + pl) * (pb + pt_);
    const float area2 = (tr + tl) * (tb + tt);
    const float uni = area1 + area2 - overlap;
    const float iou = overlap / uni;
    const float ga = fmaxf(fmaxf(pr, tr) + fmaxf(pl, tl), 0.0f) *
                     fmaxf(fmaxf(pb, tb) + fmaxf(pt_, tt), 0.0f);
    const float giou = iou - (ga - uni) / fmaxf(ga, 1e-10f);
    return 1.0f - giou;
}

__device__ __forceinline__ float bce_term(float x, float t) {
    return fmaxf(x, 0.0f) - x * t + __logf(1.0f + __expf(-fabsf(x)));
}

// ---- Kernel A: pure contiguous stream of all cls logits, negative branch ----
// r0/r7/r8/r9 all converge at main ~= 38-44 us with class-strided reads
// (~2.5 TB/s effective) while the harness fill streams 6.6 TB/s. This kernel
// reads cls in EXACT layout order (fill-like): no strides, no targets, no
// compares. Positive-class terms are corrected by kernel B (focal is 99%
// negative-branch: P(target==0) = 1/81).
__global__ __launch_bounds__(256) void fcos_neg(Ptrs p) {
    const int bx = (int)blockIdx.x;

    int lvl, b, cnk, slot, CH, TOT;
    if (bx < 1536)      { lvl = 0; b = bx / 96;  cnk = bx - 96 * b;
                          slot = cnk;        CH = 2667; TOT = 256000; }
    else if (bx < 1920) { const int r = bx - 1536; lvl = 1; b = r / 24; cnk = r - 24 * b;
                          slot = 96 + cnk;   CH = 2667; TOT = 64000; }
    else if (bx < 2016) { const int r = bx - 1920; lvl = 2; b = r / 6;  cnk = r - 6 * b;
                          slot = 120 + cnk;  CH = 2667; TOT = 16000; }
    else if (bx < 2048) { const int r = bx - 2016; lvl = 3; b = r >> 1; cnk = r & 1;
                          slot = 126 + cnk;  CH = 2080; TOT = 4160; }
    else                { const int r = bx - 2048; lvl = 4; b = r;      cnk = 0;
                          slot = 128;        CH = 1120; TOT = 1120; }

    const vfloat4* bp = (const vfloat4*)(p.cls[lvl] + (size_t)b * 4 * TOT);
    const int i0   = cnk * CH;
    const int iend = min(i0 + CH, TOT);

    float acc = 0.f;
    #pragma unroll 2
    for (int i = i0 + (int)threadIdx.x; i < iend; i += 256) {
        const vfloat4 v = bp[i];
        acc += (focal_term(v.x, false) + focal_term(v.y, false)) +
               (focal_term(v.z, false) + focal_term(v.w, false));
    }

    #pragma unroll
    for (int d = 32; d; d >>= 1) acc += __shfl_down(acc, d);

    __shared__ float red[4];
    const int wave = threadIdx.x >> 6;
    if ((threadIdx.x & 63) == 0) red[wave] = acc;
    __syncthreads();
    if (threadIdx.x == 0)
        p.ws[b * SLOTS_PER_B + slot] = (red[0] + red[1]) + (red[2] + red[3]);
}

// ---- Kernel B: positive-class correction + cnt BCE + GIoU ----
__global__ __launch_bounds__(256) void fcos_pos(Ptrs p) {
    const int bid = (int)blockIdx.x;        // 0..271
    const int b   = bid / NXQ;
    const int xq  = bid - b * NXQ;
    const int fq  = xq * 256 + (int)threadIdx.x;

    int lvl, qb, hw, off;
    if (fq < 3200)      { lvl = 0; qb = 0;    hw = 12800; off = 0;     }
    else if (fq < 4000) { lvl = 1; qb = 3200; hw = 3200;  off = 12800; }
    else if (fq < 4200) { lvl = 2; qb = 4000; hw = 800;   off = 16000; }
    else if (fq < 4252) { lvl = 3; qb = 4200; hw = 208;   off = 16800; }
    else                { lvl = 4; qb = 4252; hw = 56;    off = 17008; }
    const bool active = (fq < QPB);

    float corr = 0.f, acnt = 0.f, areg = 0.f, apos = 0.f;

    if (active) {
        const int s0  = (fq - qb) << 2;
        const int gs0 = b * S_TOTAL + off + s0;
        const int4 tq = *(const int4*)(p.cls_t + gs0);
        const float* cb = p.cls[lvl] + (size_t)(b * NC) * hw + s0;

        // per-element gather of the target-class logit (L3-warm after A)
        #pragma unroll
        for (int e = 0; e < 4; ++e) {
            const int ti = (e == 0) ? tq.x : (e == 1) ? tq.y : (e == 2) ? tq.z : tq.w;
            if (ti > 0) {
                const float x = cb[(size_t)(ti - 1) * hw + e];
                corr += focal_term(x, true) - focal_term(x, false);
            }
        }

        // cnt BCE + GIoU (unchanged from r9)
        const float4 tC  = *(const float4*)(p.cnt_t + gs0);
        const float4 xc  = *(const float4*)(p.cnt[lvl] + (size_t)(b * hw + s0));
        const float m0 = (tC.x > -1.0f) ? 1.0f : 0.0f;
        const float m1 = (tC.y > -1.0f) ? 1.0f : 0.0f;
        const float m2 = (tC.z > -1.0f) ? 1.0f : 0.0f;
        const float m3 = (tC.w > -1.0f) ? 1.0f : 0.0f;
        apos = m0 + m1 + m2 + m3;
        acnt = bce_term(xc.x, tC.x) * m0 + bce_term(xc.y, tC.y) * m1 +
               bce_term(xc.z, tC.z) * m2 + bce_term(xc.w, tC.w) * m3;

        const float* rp  = p.reg[lvl] + (size_t)(b * 4 * hw + s0);
        const float4 pl  = *(const float4*)(rp);
        const float4 pt_ = *(const float4*)(rp + (size_t)hw);
        const float4 pr  = *(const float4*)(rp + (size_t)(2 * hw));
        const float4 pb  = *(const float4*)(rp + (size_t)(3 * hw));
        const float4 t0  = *(const float4*)(p.reg_t + (size_t)(gs0 + 0) * 4);
        const float4 t1  = *(const float4*)(p.reg_t + (size_t)(gs0 + 1) * 4);
        const float4 t2  = *(const float4*)(p.reg_t + (size_t)(gs0 + 2) * 4);
        const float4 t3  = *(const float4*)(p.reg_t + (size_t)(gs0 + 3) * 4);

        areg = giou_term(pl.x, pt_.x, pr.x, pb.x, t0.x, t0.y, t0.z, t0.w) * m0 +
               giou_term(pl.y, pt_.y, pr.y, pb.y, t1.x, t1.y, t1.z, t1.w) * m1 +
               giou_term(pl.z, pt_.z, pr.z, pb.z, t2.x, t2.y, t2.z, t2.w) * m2 +
               giou_term(pl.w, pt_.w, pr.w, pb.w, t3.x, t3.y, t3.z, t3.w) * m3;
    }

    #pragma unroll
    for (int d = 32; d; d >>= 1) {
        corr += __shfl_down(corr, d);
        acnt += __shfl_down(acnt, d);
        areg += __shfl_down(areg, d);
        apos += __shfl_down(apos, d);
    }

    __shared__ float red[4][4];
    const int wave = threadIdx.x >> 6;
    const int lane = threadIdx.x & 63;
    if (lane == 0) {
        red[0][wave] = corr; red[1][wave] = acnt;
        red[2][wave] = areg; red[3][wave] = apos;
    }
    __syncthreads();
    if (threadIdx.x == 0) {
        const int s = b * NXQ + xq;
        p.ws[WSB + 0 * NBXQ + s] = red[0][0] + red[0][1] + red[0][2] + red[0][3];
        p.ws[WSB + 1 * NBXQ + s] = red[1][0] + red[1][1] + red[1][2] + red[1][3];
        p.ws[WSB + 2 * NBXQ + s] = red[2][0] + red[2][1] + red[2][2] + red[2][3];
        p.ws[WSB + 3 * NBXQ + s] = red[3][0] + red[3][1] + red[3][2] + red[3][3];
    }
}

// ---- Kernel C: final reduction (stream-ordered after A and B) ----
__global__ __launch_bounds__(256) void fcos_finalize(const float* __restrict__ ws,
                                                     float* __restrict__ out) {
    __shared__ float s[4][256];
    __shared__ float lb[3][NB];
    const int t = (int)threadIdx.x;
    const int b = t >> 4;                   // 0..15
    const int k = t & 15;                   // 0..15

    float qc = 0.f;
    for (int i = k; i < SLOTS_PER_B; i += 16) qc += ws[b * SLOTS_PER_B + i];
    float q1 = 0.f, q2 = 0.f, q3 = 0.f;
    for (int i = k; i < NXQ; i += 16) {
        const int sl = b * NXQ + i;
        qc += ws[WSB + 0 * NBXQ + sl];
        q1 += ws[WSB + 1 * NBXQ + sl];
        q2 += ws[WSB + 2 * NBXQ + sl];
        q3 += ws[WSB + 3 * NBXQ + sl];
    }
    s[0][t] = qc; s[1][t] = q1; s[2][t] = q2; s[3][t] = q3;
    __syncthreads();

    if (t < NB) {
        float cls = 0.f, cnt = 0.f, reg = 0.f, pos = 0.f;
        #pragma unroll
        for (int kk = 0; kk < 16; ++kk) {
            cls += s[0][t * 16 + kk];
            cnt += s[1][t * 16 + kk];
            reg += s[2][t * 16 + kk];
            pos += s[3][t * 16 + kk];
        }
        const float np = fmaxf(pos, 1.0f);
        lb[0][t] = cls / np;
        lb[1][t] = cnt / np;
        lb[2][t] = reg / np;
    }
    __syncthreads();

    if (t == 0) {
        float l0 = 0.f, l1 = 0.f, l2 = 0.f;
        #pragma unroll
        for (int bb = 0; bb < NB; ++bb) {
            l0 += lb[0][bb]; l1 += lb[1][bb]; l2 += lb[2][bb];
        }
        l0 *= (1.0f / NB); l1 *= (1.0f / NB); l2 *= (1.0f / NB);
        out[0] = l0;
        out[1] = l1;
        out[2] = l2;
        out[3] = l0 + l1 + l2;
    }
}

extern "C" void kernel_launch(void* const* d_in, const int* in_sizes, int n_in,
                              void* d_out, int out_size, void* d_ws, size_t ws_size,
                              hipStream_t stream) {
    Ptrs p;
    for (int i = 0; i < 5; ++i) {
        p.cls[i] = (const float*)d_in[3 * i + 0];
        p.cnt[i] = (const float*)d_in[3 * i + 1];
        p.reg[i] = (const float*)d_in[3 * i + 2];
    }
    p.cnt_t = (const float*)d_in[15];
    p.reg_t = (const float*)d_in[16];
    p.cls_t = (const int*)  d_in[17];
    p.ws    = (float*)d_ws;
    p.out   = (float*)d_out;

    fcos_neg<<<dim3(NA_BLOCKS), 256, 0, stream>>>(p);
    fcos_pos<<<dim3(NBXQ), 256, 0, stream>>>(p);
    fcos_finalize<<<dim3(1), 256, 0, stream>>>((const float*)d_ws, (float*)d_out);
}

// Round 11
// 153.507 us; speedup vs baseline: 1.0510x; 1.0510x over previous
//
#include <hip/hip_runtime.h>

#define S_TOTAL 17064
#define NB 16
#define NC 80
#define QPB 4266              // location-quads per batch image (sum hw/4)
#define NXQ 17                // quad-chunks of 256 for the cnt/GIoU blocks

// Sweep geometry: per (level,b) span = 80*hw4 float4s, swept by Kb blocks
// in grid-stride (contiguous advancing front of Kb*4KB):
// L0 hw4=3200 span=256000 Kb=96 | L1 800/64000/24 | L2 200/16000/6
// L3 52/4160/2 | L4 14/1120/1
#define NA_BLOCKS 2064        // 16*(96+24+6+2+1)
#define SLOTS_PER_B 129       // cls partial slots per b: 96+24+6+2+1
#define WSB 2064              // ws: [0,2064) cls partials; 4 planes of 272 after
#define NBXQ (NB * NXQ)       // 272
#define TOTAL_GRID (NA_BLOCKS + NBXQ)   // 2336

typedef float vfloat4 __attribute__((ext_vector_type(4)));

struct Ptrs {
    const float* cls[5];
    const float* cnt[5];
    const float* reg[5];
    const float* cnt_t;   // [B,S,1]
    const float* reg_t;   // [B,S,4]
    const int*   cls_t;   // [B,S,1] int32 on device
    float*       ws;
    float*       out;
};

__device__ __forceinline__ float focal_term(float x, bool o) {
    const float xs = o ? x : -x;            // p_t = sigmoid(xs)
    const float af = o ? 0.25f : 0.75f;
    const float em = __expf(-xs);
    const float pt = 1.0f / (1.0f + em);
    const float q  = em * pt;               // 1 - p_t
    return af * q * q * __logf(1.0f + em);  // -af*(1-pt)^2*log(pt)
}

__device__ __forceinline__ float giou_term(float pl, float pt_, float pr, float pb,
                                           float tl, float tt, float tr, float tb) {
    const float overlap = fmaxf(fminf(pr, tr) + fminf(pl, tl), 0.0f) *
                          fmaxf(fminf(pb, tb) + fminf(pt_, tt), 0.0f);
    const float area1 = (pr + pl) * (pb + pt_);
    const float area2 = (tr + tl) * (tb + tt);
    const float uni = area1 + area2 - overlap;
    const float iou = overlap / uni;
    const float ga = fmaxf(fmaxf(pr, tr) + fmaxf(pl, tl), 0.0f) *
                     fmaxf(fmaxf(pb, tb) + fmaxf(pt_, tt), 0.0f);
    const float giou = iou - (ga - uni) / fmaxf(ga, 1e-10f);
    return 1.0f - giou;
}

__device__ __forceinline__ float bce_term(float x, float t) {
    return fmaxf(x, 0.0f) - x * t + __logf(1.0f + __expf(-fabsf(x)));
}

__device__ __forceinline__ float focal_quad(vfloat4 v, int4 t, int c1) {
    return (focal_term(v.x, t.x == c1) + focal_term(v.y, t.y == c1)) +
           (focal_term(v.z, t.z == c1) + focal_term(v.w, t.w == c1));
}

// Grid-stride sweep of one (level,b) cls span in LAYOUT order, targets inline.
// HW4 compile-time -> div is a magic-mul. Hand-paired iterations keep 4 loads
// (2 cls f4 + 2 cls_t int4) in flight. ct is the b-local target row (L2-hot).
template <int HW4>
__device__ __forceinline__ float sweep_cls(const vfloat4* __restrict__ bp,
                                           const int* __restrict__ ct,
                                           int u0, int stride) {
    const int SPAN = NC * HW4;
    float a0 = 0.f, a1 = 0.f;
    int u = u0;
    for (; u + stride < SPAN; u += 2 * stride) {
        const int ub = u + stride;
        const vfloat4 va = bp[u];
        const vfloat4 vb = bp[ub];
        const int ca = u / HW4;
        const int cb = ub / HW4;
        const int4 ta = *(const int4*)(ct + ((u  - ca * HW4) << 2));
        const int4 tb = *(const int4*)(ct + ((ub - cb * HW4) << 2));
        a0 += focal_quad(va, ta, ca + 1);
        a1 += focal_quad(vb, tb, cb + 1);
    }
    if (u < SPAN) {
        const vfloat4 v = bp[u];
        const int c = u / HW4;
        const int4 t = *(const int4*)(ct + ((u - c * HW4) << 2));
        a0 += focal_quad(v, t, c + 1);
    }
    return a0 + a1;
}

// bx < 2064: cls sweep block (level,b,chunk). bx >= 2064: cnt/GIoU block.
// No atomics (r6: single-address ACQ_REL serialized blocks ~65ns each).
// Sequential-front rationale: r0/r7/r8/r9 converge at main~=38-44us with
// scattered 1KB reads (~2.5TB/s eff); harness fill streams 6.6TB/s. 16
// coordinated fronts of Kb*4KB advancing in layout order reproduce the
// fill's DRAM row locality; positives compare inline against the L2-hot
// 1MB cls_t region (no separate gather pass -- r10's B overhead).
__global__ __launch_bounds__(256) void fcos_main(Ptrs p) {
    const int bx = (int)blockIdx.x;
    __shared__ float red[4][4];
    const int wave = threadIdx.x >> 6;
    const int lane = threadIdx.x & 63;

    if (bx < NA_BLOCKS) {
        int lvl, b, cnk, Kb, slot;
        if (bx < 1536)      { lvl = 0; b = bx / 96;  cnk = bx - 96 * b;  Kb = 96; slot = cnk; }
        else if (bx < 1920) { const int r = bx - 1536; lvl = 1; b = r / 24; cnk = r - 24 * b; Kb = 24; slot = 96 + cnk; }
        else if (bx < 2016) { const int r = bx - 1920; lvl = 2; b = r / 6;  cnk = r - 6 * b;  Kb = 6;  slot = 120 + cnk; }
        else if (bx < 2048) { const int r = bx - 2016; lvl = 3; b = r >> 1; cnk = r & 1;      Kb = 2;  slot = 126 + cnk; }
        else                { lvl = 4; b = bx - 2048;  cnk = 0;            Kb = 1;            slot = 128; }

        const int u0     = cnk * 256 + (int)threadIdx.x;
        const int stride = Kb * 256;
        float acc = 0.f;
        switch (lvl) {
            case 0: acc = sweep_cls<3200>((const vfloat4*)p.cls[0] + (size_t)b * (NC * 3200),
                                          p.cls_t + b * S_TOTAL + 0,     u0, stride); break;
            case 1: acc = sweep_cls<800>((const vfloat4*)p.cls[1] + (size_t)b * (NC * 800),
                                          p.cls_t + b * S_TOTAL + 12800, u0, stride); break;
            case 2: acc = sweep_cls<200>((const vfloat4*)p.cls[2] + (size_t)b * (NC * 200),
                                          p.cls_t + b * S_TOTAL + 16000, u0, stride); break;
            case 3: acc = sweep_cls<52>((const vfloat4*)p.cls[3] + (size_t)b * (NC * 52),
                                          p.cls_t + b * S_TOTAL + 16800, u0, stride); break;
            default: acc = sweep_cls<14>((const vfloat4*)p.cls[4] + (size_t)b * (NC * 14),
                                          p.cls_t + b * S_TOTAL + 17008, u0, stride); break;
        }

        #pragma unroll
        for (int d = 32; d; d >>= 1) acc += __shfl_down(acc, d);
        if (lane == 0) red[0][wave] = acc;
        __syncthreads();
        if (threadIdx.x == 0)
            p.ws[b * SLOTS_PER_B + slot] = (red[0][0] + red[0][1]) + (red[0][2] + red[0][3]);

    } else {
        // ---- cnt BCE + GIoU blocks ----
        const int bid = bx - NA_BLOCKS;     // 0..271
        const int b   = bid / NXQ;
        const int xq  = bid - b * NXQ;
        const int fq  = xq * 256 + (int)threadIdx.x;

        int lvl, qb, hw, off;
        if (fq < 3200)      { lvl = 0; qb = 0;    hw = 12800; off = 0;     }
        else if (fq < 4000) { lvl = 1; qb = 3200; hw = 3200;  off = 12800; }
        else if (fq < 4200) { lvl = 2; qb = 4000; hw = 800;   off = 16000; }
        else if (fq < 4252) { lvl = 3; qb = 4200; hw = 208;   off = 16800; }
        else                { lvl = 4; qb = 4252; hw = 56;    off = 17008; }
        const bool active = (fq < QPB);

        float acnt = 0.f, areg = 0.f, apos = 0.f;
        if (active) {
            const int s0  = (fq - qb) << 2;
            const int gs0 = b * S_TOTAL + off + s0;
            const float4 tC  = *(const float4*)(p.cnt_t + gs0);
            const float4 xc  = *(const float4*)(p.cnt[lvl] + (size_t)(b * hw + s0));
            const float m0 = (tC.x > -1.0f) ? 1.0f : 0.0f;
            const float m1 = (tC.y > -1.0f) ? 1.0f : 0.0f;
            const float m2 = (tC.z > -1.0f) ? 1.0f : 0.0f;
            const float m3 = (tC.w > -1.0f) ? 1.0f : 0.0f;
            apos = m0 + m1 + m2 + m3;
            acnt = bce_term(xc.x, tC.x) * m0 + bce_term(xc.y, tC.y) * m1 +
                   bce_term(xc.z, tC.z) * m2 + bce_term(xc.w, tC.w) * m3;

            const float* rp  = p.reg[lvl] + (size_t)(b * 4 * hw + s0);
            const float4 pl  = *(const float4*)(rp);
            const float4 pt_ = *(const float4*)(rp + (size_t)hw);
            const float4 pr  = *(const float4*)(rp + (size_t)(2 * hw));
            const float4 pb  = *(const float4*)(rp + (size_t)(3 * hw));
            const float4 t0  = *(const float4*)(p.reg_t + (size_t)(gs0 + 0) * 4);
            const float4 t1  = *(const float4*)(p.reg_t + (size_t)(gs0 + 1) * 4);
            const float4 t2  = *(const float4*)(p.reg_t + (size_t)(gs0 + 2) * 4);
            const float4 t3  = *(const float4*)(p.reg_t + (size_t)(gs0 + 3) * 4);

            areg = giou_term(pl.x, pt_.x, pr.x, pb.x, t0.x, t0.y, t0.z, t0.w) * m0 +
                   giou_term(pl.y, pt_.y, pr.y, pb.y, t1.x, t1.y, t1.z, t1.w) * m1 +
                   giou_term(pl.z, pt_.z, pr.z, pb.z, t2.x, t2.y, t2.z, t2.w) * m2 +
                   giou_term(pl.w, pt_.w, pr.w, pb.w, t3.x, t3.y, t3.z, t3.w) * m3;
        }

        #pragma unroll
        for (int d = 32; d; d >>= 1) {
            acnt += __shfl_down(acnt, d);
            areg += __shfl_down(areg, d);
            apos += __shfl_down(apos, d);
        }
        if (lane == 0) {
            red[1][wave] = acnt; red[2][wave] = areg; red[3][wave] = apos;
        }
        __syncthreads();
        if (threadIdx.x == 0) {
            const int s = b * NXQ + xq;
            p.ws[WSB + 0 * NBXQ + s] = 0.0f;
            p.ws[WSB + 1 * NBXQ + s] = red[1][0] + red[1][1] + red[1][2] + red[1][3];
            p.ws[WSB + 2 * NBXQ + s] = red[2][0] + red[2][1] + red[2][2] + red[2][3];
            p.ws[WSB + 3 * NBXQ + s] = red[3][0] + red[3][1] + red[3][2] + red[3][3];
        }
    }
}

// ---- finalize (stream-ordered) ----
__global__ __launch_bounds__(256) void fcos_finalize(const float* __restrict__ ws,
                                                     float* __restrict__ out) {
    __shared__ float s[4][256];
    __shared__ float lb[3][NB];
    const int t = (int)threadIdx.x;
    const int b = t >> 4;                   // 0..15
    const int k = t & 15;                   // 0..15

    float qc = 0.f;
    for (int i = k; i < SLOTS_PER_B; i += 16) qc += ws[b * SLOTS_PER_B + i];
    float q1 = 0.f, q2 = 0.f, q3 = 0.f;
    for (int i = k; i < NXQ; i += 16) {
        const int sl = b * NXQ + i;
        qc += ws[WSB + 0 * NBXQ + sl];
        q1 += ws[WSB + 1 * NBXQ + sl];
        q2 += ws[WSB + 2 * NBXQ + sl];
        q3 += ws[WSB + 3 * NBXQ + sl];
    }
    s[0][t] = qc; s[1][t] = q1; s[2][t] = q2; s[3][t] = q3;
    __syncthreads();

    if (t < NB) {
        float cls = 0.f, cnt = 0.f, reg = 0.f, pos = 0.f;
        #pragma unroll
        for (int kk = 0; kk < 16; ++kk) {
            cls += s[0][t * 16 + kk];
            cnt += s[1][t * 16 + kk];
            reg += s[2][t * 16 + kk];
            pos += s[3][t * 16 + kk];
        }
        const float np = fmaxf(pos, 1.0f);
        lb[0][t] = cls / np;
        lb[1][t] = cnt / np;
        lb[2][t] = reg / np;
    }
    __syncthreads();

    if (t == 0) {
        float l0 = 0.f, l1 = 0.f, l2 = 0.f;
        #pragma unroll
        for (int bb = 0; bb < NB; ++bb) {
            l0 += lb[0][bb]; l1 += lb[1][bb]; l2 += lb[2][bb];
        }
        l0 *= (1.0f / NB); l1 *= (1.0f / NB); l2 *= (1.0f / NB);
        out[0] = l0;
        out[1] = l1;
        out[2] = l2;
        out[3] = l0 + l1 + l2;
    }
}

extern "C" void kernel_launch(void* const* d_in, const int* in_sizes, int n_in,
                              void* d_out, int out_size, void* d_ws, size_t ws_size,
                              hipStream_t stream) {
    Ptrs p;
    for (int i = 0; i < 5; ++i) {
        p.cls[i] = (const float*)d_in[3 * i + 0];
        p.cnt[i] = (const float*)d_in[3 * i + 1];
        p.reg[i] = (const float*)d_in[3 * i + 2];
    }
    p.cnt_t = (const float*)d_in[15];
    p.reg_t = (const float*)d_in[16];
    p.cls_t = (const int*)  d_in[17];
    p.ws    = (float*)d_ws;
    p.out   = (float*)d_out;

    fcos_main<<<dim3(TOTAL_GRID), 256, 0, stream>>>(p);
    fcos_finalize<<<dim3(1), 256, 0, stream>>>((const float*)d_ws, (float*)d_out);
}